// Round 6
// baseline (3325.611 us; speedup 1.0000x reference)
//
#include <hip/hip_runtime.h>
#include <stdint.h>

#define BB 64
#define TN 512
#define FF 256
#define HH 512

typedef _Float16 half2v __attribute__((ext_vector_type(2)));

__device__ __forceinline__ float fdot2u(uint32_t hpair, uint32_t wpair, float acc) {
#if __has_builtin(__builtin_amdgcn_fdot2)
  return __builtin_amdgcn_fdot2(__builtin_bit_cast(half2v, hpair),
                                __builtin_bit_cast(half2v, wpair), acc, false);
#else
  asm("v_dot2_f32_f16 %0, %1, %2, %0" : "+v"(acc) : "v"(hpair), "v"(wpair));
  return acc;
#endif
}

__device__ __forceinline__ float fast_rcp(float x) {
#if __has_builtin(__builtin_amdgcn_rcpf)
  return __builtin_amdgcn_rcpf(x);
#else
  return 1.0f / x;
#endif
}

// ---------------- Phase 1: out = x @ Wx^T + bias ----------------
// M = B*T = 32768, N = H = 512, K = F = 256. 128x128 tiles, BK=32,
// 256 threads, 8x8 outputs/thread. Transposed LDS tiles [kk][row].
__global__ __launch_bounds__(256) void xproj_kernel(
    const float* __restrict__ x, const float* __restrict__ Wx,
    const float* __restrict__ bias, float* __restrict__ out)
{
  __shared__ float As[32][132];
  __shared__ float Bs[32][132];
  const int bx = blockIdx.x;
  const int mt = bx & 255, nt = bx >> 8;
  const int m0 = mt << 7, n0 = nt << 7;
  const int tid = threadIdx.x;
  const int k4 = tid & 7, li = tid >> 3;   // loader coords
  const int tc = tid & 15, tr = tid >> 4;  // compute coords
  float acc[8][8];
  #pragma unroll
  for (int i = 0; i < 8; ++i)
    #pragma unroll
    for (int j = 0; j < 8; ++j) acc[i][j] = 0.f;

  for (int kc = 0; kc < 8; ++kc) {
    const int k0 = kc << 5;
    #pragma unroll
    for (int rr = 0; rr < 4; ++rr) {
      const int i = (rr << 5) + li;
      const float4 vx = *(const float4*)(x + (size_t)(m0 + i) * FF + k0 + (k4 << 2));
      As[(k4 << 2) + 0][i] = vx.x; As[(k4 << 2) + 1][i] = vx.y;
      As[(k4 << 2) + 2][i] = vx.z; As[(k4 << 2) + 3][i] = vx.w;
      const float4 vw = *(const float4*)(Wx + (size_t)(n0 + i) * FF + k0 + (k4 << 2));
      Bs[(k4 << 2) + 0][i] = vw.x; Bs[(k4 << 2) + 1][i] = vw.y;
      Bs[(k4 << 2) + 2][i] = vw.z; Bs[(k4 << 2) + 3][i] = vw.w;
    }
    __syncthreads();
    #pragma unroll
    for (int kk = 0; kk < 32; ++kk) {
      const float4 a0 = *(const float4*)&As[kk][tr << 3];
      const float4 a1 = *(const float4*)&As[kk][(tr << 3) + 4];
      const float4 b0 = *(const float4*)&Bs[kk][tc << 3];
      const float4 b1 = *(const float4*)&Bs[kk][(tc << 3) + 4];
      const float av[8] = {a0.x, a0.y, a0.z, a0.w, a1.x, a1.y, a1.z, a1.w};
      const float bv[8] = {b0.x, b0.y, b0.z, b0.w, b1.x, b1.y, b1.z, b1.w};
      #pragma unroll
      for (int i = 0; i < 8; ++i)
        #pragma unroll
        for (int j = 0; j < 8; ++j)
          acc[i][j] = __builtin_fmaf(av[i], bv[j], acc[i][j]);
    }
    __syncthreads();
  }
  const float4 bq0 = *(const float4*)(bias + n0 + (tc << 3));
  const float4 bq1 = *(const float4*)(bias + n0 + (tc << 3) + 4);
  #pragma unroll
  for (int i = 0; i < 8; ++i) {
    float* orow = out + (size_t)(m0 + (tr << 3) + i) * HH + n0 + (tc << 3);
    *(float4*)orow       = make_float4(acc[i][0] + bq0.x, acc[i][1] + bq0.y,
                                       acc[i][2] + bq0.z, acc[i][3] + bq0.w);
    *(float4*)(orow + 4) = make_float4(acc[i][4] + bq1.x, acc[i][5] + bq1.y,
                                       acc[i][6] + bq1.z, acc[i][7] + bq1.w);
  }
}

// ---------------- Phase 2: persistent per-batch recurrence ----------------
// 64 WGs x 256 threads (4 waves = 1 wave/SIMD -> 512-reg budget/wave).
// Thread t = (ks = t>>6, jg = t&63) owns rows j = 8*jg + r (r=0..7) over
// k-slice [ks*128, ks*128+128). Wh f16: 48 pairs/row in VGPRs (384 regs,
// fits 512 budget with headroom) + 16 pairs/row in LDS (128 KiB).
// h: f32 master split over 2 channels/thread; packed f16 copy in LDS.
// xproj read from d_out, overwritten in place with output h.
__global__ __launch_bounds__(256, 1) void liquid_kernel(
    const float* __restrict__ Wh, const float* __restrict__ log_tau,
    const int* __restrict__ steps, float* __restrict__ out)
{
  __shared__ __align__(16) uint32_t wlds[32 * 256 * 4]; // 128 KiB
  __shared__ __align__(16) float    pred[4 * 512];      // 8 KiB  [ks*512 + j]
  __shared__ __align__(16) uint32_t hpk[256];           // 1 KiB packed f16 h

  const int t  = threadIdx.x;
  const int b  = blockIdx.x;
  const int ks = t >> 6;   // 0..3  k-slice
  const int jg = t & 63;   // 0..63 row group

  // ---- one-time: load Wh rows, convert to packed f16 ----
  uint32_t wreg[8][48];
  #pragma unroll
  for (int r = 0; r < 8; ++r) {
    const float* wrow = Wh + (size_t)((jg << 3) + r) * HH + (ks << 7);
    #pragma unroll
    for (int p = 0; p < 64; ++p) {
      half2v pk;
      pk.x = (_Float16)wrow[2 * p];
      pk.y = (_Float16)wrow[2 * p + 1];
      const uint32_t u = __builtin_bit_cast(uint32_t, pk);
      if (p < 48) {
        wreg[r][p] = u;
      } else {
        const int pp = p - 48;
        // layout: [((pp>>2)*8 + r)*256 + t]*4 + (pp&3) -- 16B/thread, lane-contig
        wlds[((((pp >> 2) << 3) + r) * 256 + t) * 4 + (pp & 3)] = u;
      }
    }
  }
  hpk[t] = 0u;
  float h0 = 0.f, h1 = 0.f;
  const float itau0 = __expf(-log_tau[t]);
  const float itau1 = __expf(-log_tau[t + 256]);
  int nE = steps[0]; if (nE < 1) nE = 1;
  float* outb = out + (size_t)b * TN * HH + t;
  const uint32_t* hp = hpk + (ks << 6);   // this slice's 64 h-pairs
  __syncthreads();

  for (int step = 0; step < TN; ++step) {
    const float xp0 = outb[0];      // read xproj before overwrite
    const float xp1 = outb[256];
    for (int e = 0; e < nE; ++e) {
      float acc[8] = {0.f, 0.f, 0.f, 0.f, 0.f, 0.f, 0.f, 0.f};
      // register-resident weights: chunks 0..11 (48 pairs/row)
      #pragma unroll
      for (int c = 0; c < 12; ++c) {
        const uint4 hv = *(const uint4*)(hp + (c << 2));   // broadcast b128
        #pragma unroll
        for (int r = 0; r < 8; ++r) {
          acc[r] = fdot2u(hv.x, wreg[r][(c << 2) + 0], acc[r]);
          acc[r] = fdot2u(hv.y, wreg[r][(c << 2) + 1], acc[r]);
          acc[r] = fdot2u(hv.z, wreg[r][(c << 2) + 2], acc[r]);
          acc[r] = fdot2u(hv.w, wreg[r][(c << 2) + 3], acc[r]);
        }
      }
      // LDS-resident weights: chunks 12..15 (16 pairs/row)
      #pragma unroll
      for (int c2 = 0; c2 < 4; ++c2) {
        const uint4 hv = *(const uint4*)(hp + ((12 + c2) << 2));
        #pragma unroll
        for (int r = 0; r < 8; ++r) {
          const uint4 wv = *(const uint4*)&wlds[((((c2 << 3) + r) * 256) + t) * 4];
          acc[r] = fdot2u(hv.x, wv.x, acc[r]);
          acc[r] = fdot2u(hv.y, wv.y, acc[r]);
          acc[r] = fdot2u(hv.z, wv.z, acc[r]);
          acc[r] = fdot2u(hv.w, wv.w, acc[r]);
        }
      }
      // partials: flat idx ks*512 + 8*jg + r == t*8 + r -> two b128 writes
      *(float4*)&pred[(t << 3) + 0] = make_float4(acc[0], acc[1], acc[2], acc[3]);
      *(float4*)&pred[(t << 3) + 4] = make_float4(acc[4], acc[5], acc[6], acc[7]);
      __syncthreads();
      // thread t finishes channels t and t+256
      const float s0 = xp0 + pred[t]        + pred[512 + t]
                           + pred[1024 + t] + pred[1536 + t];
      const float s1 = xp1 + pred[256 + t]  + pred[768 + t]
                           + pred[1280 + t] + pred[1792 + t];
      const float z0 = 1.f - 2.f * fast_rcp(__expf(2.f * s0) + 1.f);  // tanh(s0)
      const float z1 = 1.f - 2.f * fast_rcp(__expf(2.f * s1) + 1.f);  // tanh(s1)
      h0 += (z0 - h0) * itau0;
      h1 += (z1 - h1) * itau1;
      ((_Float16*)hpk)[t]       = (_Float16)h0;
      ((_Float16*)hpk)[t + 256] = (_Float16)h1;
      __syncthreads();
    }
    outb[0]   = h0;   // overwrite xproj slot with output
    outb[256] = h1;
    outb += HH;
  }
}

extern "C" void kernel_launch(void* const* d_in, const int* in_sizes, int n_in,
                              void* d_out, int out_size, void* d_ws, size_t ws_size,
                              hipStream_t stream) {
  const float* x       = (const float*)d_in[0];
  const float* Wx      = (const float*)d_in[1];
  const float* Wh      = (const float*)d_in[2];
  const float* bias    = (const float*)d_in[3];
  const float* log_tau = (const float*)d_in[4];
  const int*   steps   = (const int*)d_in[5];
  float* out = (float*)d_out;

  hipLaunchKernelGGL(xproj_kernel,  dim3(1024), dim3(256), 0, stream, x, Wx, bias, out);
  hipLaunchKernelGGL(liquid_kernel, dim3(64),   dim3(256), 0, stream, Wh, log_tau, steps, out);
}

// Round 13
// 1607.670 us; speedup vs baseline: 2.0686x; 2.0686x over previous
//
#include <hip/hip_runtime.h>
#include <stdint.h>

#define BB 64
#define TN 512
#define FF 256
#define HH 512

typedef _Float16 half2v __attribute__((ext_vector_type(2)));

__device__ __forceinline__ float fdot2u(uint32_t hpair, uint32_t wpair, float acc) {
#if __has_builtin(__builtin_amdgcn_fdot2)
  return __builtin_amdgcn_fdot2(__builtin_bit_cast(half2v, hpair),
                                __builtin_bit_cast(half2v, wpair), acc, false);
#else
  asm("v_dot2_f32_f16 %0, %1, %2, %0" : "+v"(acc) : "v"(hpair), "v"(wpair));
  return acc;
#endif
}

__device__ __forceinline__ float fast_rcp(float x) {
#if __has_builtin(__builtin_amdgcn_rcpf)
  return __builtin_amdgcn_rcpf(x);
#else
  return 1.0f / x;
#endif
}

// ---------------- Phase 1: out = x @ Wx^T + bias ----------------
// M = B*T = 32768, N = H = 512, K = F = 256. 128x128 tiles, BK=32,
// 256 threads, 8x8 outputs/thread. Transposed LDS tiles [kk][row].
__global__ __launch_bounds__(256) void xproj_kernel(
    const float* __restrict__ x, const float* __restrict__ Wx,
    const float* __restrict__ bias, float* __restrict__ out)
{
  __shared__ float As[32][132];
  __shared__ float Bs[32][132];
  const int bx = blockIdx.x;
  const int mt = bx & 255, nt = bx >> 8;
  const int m0 = mt << 7, n0 = nt << 7;
  const int tid = threadIdx.x;
  const int k4 = tid & 7, li = tid >> 3;   // loader coords
  const int tc = tid & 15, tr = tid >> 4;  // compute coords
  float acc[8][8];
  #pragma unroll
  for (int i = 0; i < 8; ++i)
    #pragma unroll
    for (int j = 0; j < 8; ++j) acc[i][j] = 0.f;

  for (int kc = 0; kc < 8; ++kc) {
    const int k0 = kc << 5;
    #pragma unroll
    for (int rr = 0; rr < 4; ++rr) {
      const int i = (rr << 5) + li;
      const float4 vx = *(const float4*)(x + (size_t)(m0 + i) * FF + k0 + (k4 << 2));
      As[(k4 << 2) + 0][i] = vx.x; As[(k4 << 2) + 1][i] = vx.y;
      As[(k4 << 2) + 2][i] = vx.z; As[(k4 << 2) + 3][i] = vx.w;
      const float4 vw = *(const float4*)(Wx + (size_t)(n0 + i) * FF + k0 + (k4 << 2));
      Bs[(k4 << 2) + 0][i] = vw.x; Bs[(k4 << 2) + 1][i] = vw.y;
      Bs[(k4 << 2) + 2][i] = vw.z; Bs[(k4 << 2) + 3][i] = vw.w;
    }
    __syncthreads();
    #pragma unroll
    for (int kk = 0; kk < 32; ++kk) {
      const float4 a0 = *(const float4*)&As[kk][tr << 3];
      const float4 a1 = *(const float4*)&As[kk][(tr << 3) + 4];
      const float4 b0 = *(const float4*)&Bs[kk][tc << 3];
      const float4 b1 = *(const float4*)&Bs[kk][(tc << 3) + 4];
      const float av[8] = {a0.x, a0.y, a0.z, a0.w, a1.x, a1.y, a1.z, a1.w};
      const float bv[8] = {b0.x, b0.y, b0.z, b0.w, b1.x, b1.y, b1.z, b1.w};
      #pragma unroll
      for (int i = 0; i < 8; ++i)
        #pragma unroll
        for (int j = 0; j < 8; ++j)
          acc[i][j] = __builtin_fmaf(av[i], bv[j], acc[i][j]);
    }
    __syncthreads();
  }
  const float4 bq0 = *(const float4*)(bias + n0 + (tc << 3));
  const float4 bq1 = *(const float4*)(bias + n0 + (tc << 3) + 4);
  #pragma unroll
  for (int i = 0; i < 8; ++i) {
    float* orow = out + (size_t)(m0 + (tr << 3) + i) * HH + n0 + (tc << 3);
    *(float4*)orow       = make_float4(acc[i][0] + bq0.x, acc[i][1] + bq0.y,
                                       acc[i][2] + bq0.z, acc[i][3] + bq0.w);
    *(float4*)(orow + 4) = make_float4(acc[i][4] + bq1.x, acc[i][5] + bq1.y,
                                       acc[i][6] + bq1.z, acc[i][7] + bq1.w);
  }
}

// ---------------- Phase 2: persistent per-batch recurrence ----------------
// 64 WGs x 512 threads (8 waves = 2 waves/SIMD). Thread t = (ks=t>>7,
// jg=t&127) owns rows j = 4*jg + r (r=0..3) over k-slice [ks*128,+128).
// Wh f16: 48 pairs/row in ARCH VGPRs (192 words; demand ~227 <= 256 arch
// cap) + 16 pairs/row in LDS (128 KiB). gfx950 fact (R6 counters): VALU
// reads only the 256 arch VGPRs; AGPRs need moves. 256-thr variant (384
// words) hit that wall -> 3165us. R3's (512,1) let the occupancy heuristic
// pick 128 regs + spill -> 1880us. (512,2) pins budget = 512/2 = 256.
__global__ __launch_bounds__(512, 2) void liquid_kernel(
    const float* __restrict__ Wh, const float* __restrict__ log_tau,
    const int* __restrict__ steps, float* __restrict__ out)
{
  __shared__ __align__(16) uint32_t wlds[16 * 512 * 4]; // 128 KiB
  __shared__ __align__(16) float    pred[4 * 512];      // 8 KiB  [ks*512 + j]
  __shared__ __align__(16) uint32_t hpk[256];           // 1 KiB packed f16 h

  const int t  = threadIdx.x;
  const int b  = blockIdx.x;
  const int ks = t >> 7;
  const int jg = t & 127;

  // ---- one-time: load Wh rows, convert to packed f16 ----
  uint32_t wreg[4][48];
  #pragma unroll
  for (int r = 0; r < 4; ++r) {
    const float* wrow = Wh + (size_t)((jg << 2) + r) * HH + (ks << 7);
    #pragma unroll
    for (int p = 0; p < 64; ++p) {
      half2v pk;
      pk.x = (_Float16)wrow[2 * p];
      pk.y = (_Float16)wrow[2 * p + 1];
      const uint32_t u = __builtin_bit_cast(uint32_t, pk);
      if (p < 48) {
        wreg[r][p] = u;
      } else {
        const int pp = p - 48;
        // layout: [(c2*4 + r)*512 + t]*4 + q   (16B/thread/(c2,r), lane-contig)
        wlds[((((pp >> 2) << 2) + r) * 512 + t) * 4 + (pp & 3)] = u;
      }
    }
  }
  if (t < 256) hpk[t] = 0u;
  float h = 0.f;
  const float itau = __expf(-log_tau[t]);   // 1/tau, dt = 1
  int nE = steps[0]; if (nE < 1) nE = 1;
  float* outb = out + (size_t)b * TN * HH + t;
  const uint32_t* hp = hpk + (ks << 6);     // this slice's 64 h-pairs
  __syncthreads();

  for (int step = 0; step < TN; ++step) {
    const float xpv = *outb;                // read xproj before overwrite
    for (int e = 0; e < nE; ++e) {
      float acc[4] = {0.f, 0.f, 0.f, 0.f};
      // register-resident weights: chunks 0..11 (48 pairs/row)
      #pragma unroll
      for (int c = 0; c < 12; ++c) {
        const uint4 hv = *(const uint4*)(hp + (c << 2));   // broadcast b128
        #pragma unroll
        for (int r = 0; r < 4; ++r) {
          acc[r] = fdot2u(hv.x, wreg[r][(c << 2) + 0], acc[r]);
          acc[r] = fdot2u(hv.y, wreg[r][(c << 2) + 1], acc[r]);
          acc[r] = fdot2u(hv.z, wreg[r][(c << 2) + 2], acc[r]);
          acc[r] = fdot2u(hv.w, wreg[r][(c << 2) + 3], acc[r]);
        }
      }
      // LDS-resident weights: chunks 12..15 (16 pairs/row)
      #pragma unroll
      for (int c2 = 0; c2 < 4; ++c2) {
        const uint4 hv = *(const uint4*)(hp + ((12 + c2) << 2));
        #pragma unroll
        for (int r = 0; r < 4; ++r) {
          const uint4 wv = *(const uint4*)&wlds[(((c2 << 2) + r) * 512 + t) * 4];
          acc[r] = fdot2u(hv.x, wv.x, acc[r]);
          acc[r] = fdot2u(hv.y, wv.y, acc[r]);
          acc[r] = fdot2u(hv.z, wv.z, acc[r]);
          acc[r] = fdot2u(hv.w, wv.w, acc[r]);
        }
      }
      // partials: flat idx ks*512 + (4*jg + r) == t*4 + r -> b128 write
      *(float4*)&pred[t << 2] = make_float4(acc[0], acc[1], acc[2], acc[3]);
      __syncthreads();
      // thread t finishes channel t
      const float s  = xpv + pred[t] + pred[512 + t] + pred[1024 + t] + pred[1536 + t];
      const float ex = __expf(2.f * s);
      const float z  = 1.f - 2.f * fast_rcp(ex + 1.f);  // tanh(s)
      h += (z - h) * itau;
      ((_Float16*)hpk)[t] = (_Float16)h;
      __syncthreads();
    }
    *outb = h;                              // overwrite xproj slot with output
    outb += HH;
  }
}

extern "C" void kernel_launch(void* const* d_in, const int* in_sizes, int n_in,
                              void* d_out, int out_size, void* d_ws, size_t ws_size,
                              hipStream_t stream) {
  const float* x       = (const float*)d_in[0];
  const float* Wx      = (const float*)d_in[1];
  const float* Wh      = (const float*)d_in[2];
  const float* bias    = (const float*)d_in[3];
  const float* log_tau = (const float*)d_in[4];
  const int*   steps   = (const int*)d_in[5];
  float* out = (float*)d_out;

  hipLaunchKernelGGL(xproj_kernel,  dim3(1024), dim3(256), 0, stream, x, Wx, bias, out);
  hipLaunchKernelGGL(liquid_kernel, dim3(64),   dim3(512), 0, stream, Wh, log_tau, steps, out);
}